// Round 5
// baseline (632.053 us; speedup 1.0000x reference)
//
#include <hip/hip_runtime.h>
#include <math.h>

#define N_NODES 100000
#define N_EDGES 1600000
#define NCHUNK 98      // ceil(N_NODES / 1024)
#define NBKT 16        // dst-range buckets (6250 nodes each)
#define BCAP 20000     // capacity per (bucket, xcd-replica); mean 12.5K, +69 sigma
#define BPB 64         // place blocks per bucket

// ws layout (128B-aligned):
static constexpr size_t OFF_CNT  = 0;          // int[N] degree histogram
static constexpr size_t OFF_BCUR = 400000;     // int[16*8] bucket replica cursors
static constexpr size_t OFF_DINV = 400512;     // float[N]
static constexpr size_t OFF_ROW  = 800512;     // int[N] CSR row start
static constexpr size_t OFF_CUR  = 1200512;    // int[N] placement cursor
static constexpr size_t OFF_SPN  = 1600512;    // int[98] chunk spine
static constexpr size_t OFF_SSRC = 1601024;    // int[E] src sorted by dst
static constexpr size_t OFF_A    = 8001152;    // float[N*128]
static constexpr size_t OFF_B    = 59201152;   // float[N*128]; pairs alias here
// pairs (u64[16*8*20000] = 20.48 MB) alias OFF_B: consumed by k_place before
// gather1 first writes bufB. total ws = 110,401,152 B (same as round 4).

// Pass A: stream edges; fused degree hist; LDS-binned bucket scatter of
// (dst,src) pairs into per-(bucket, bid&7) regions -> contiguous ~128B runs.
__global__ __launch_bounds__(256) void k_bucket(
    const int* __restrict__ src, const int* __restrict__ dst,
    int* __restrict__ cnt, int* __restrict__ bcur,
    unsigned long long* __restrict__ pairs)
{
    __shared__ int lcnt[NBKT];
    __shared__ int lbase[NBKT];
    const int tid = threadIdx.x;
    if (tid < NBKT) lcnt[tid] = 0;
    __syncthreads();
    const int e = blockIdx.x * 256 + tid;
    int b = 0, rank = 0, s = 0, d = 0;
    const bool ok = e < N_EDGES;
    if (ok) {
        s = src[e]; d = dst[e];
        atomicAdd(&cnt[d], 1);                  // fused degree histogram
        b = d / 6250;                           // compiler emits magic-mul
        rank = atomicAdd(&lcnt[b], 1);          // LDS rank
    }
    __syncthreads();
    if (tid < NBKT) {
        int n = lcnt[tid];
        lbase[tid] = n ? atomicAdd(&bcur[tid * 8 + (blockIdx.x & 7)], n) : 0;
    }
    __syncthreads();
    if (ok) {
        int pos = lbase[b] + rank;
        if (pos < BCAP)                         // statistically impossible overflow guard
            pairs[(size_t)(b * 8 + (blockIdx.x & 7)) * BCAP + pos] =
                ((unsigned long long)(unsigned int)d << 32) | (unsigned int)s;
    }
}

// per-chunk sums (chunk = 1024 elems)
__global__ __launch_bounds__(256) void k_sum(const int* __restrict__ cnt,
                                             int* __restrict__ spn) {
    __shared__ int sm[256];
    int chunk = blockIdx.x, t = threadIdx.x;
    int base = chunk * 1024 + t * 4;
    int v = 0;
    #pragma unroll
    for (int k = 0; k < 4; ++k) { int i = base + k; if (i < N_NODES) v += cnt[i]; }
    sm[t] = v; __syncthreads();
    for (int off = 128; off > 0; off >>= 1) {
        if (t < off) sm[t] += sm[t + off];
        __syncthreads();
    }
    if (t == 0) spn[chunk] = sm[0];
}

__global__ __launch_bounds__(64) void k_spine(int* __restrict__ spn) {
    if (threadIdx.x == 0) {
        int run = 0;
        for (int i = 0; i < NCHUNK; ++i) { int c = spn[i]; spn[i] = run; run += c; }
    }
}

// chunk-local exclusive scan + spine -> row/cur; fused dinv = rsqrt(deg+1)
__global__ __launch_bounds__(256) void k_scan(const int* __restrict__ cnt,
                                              const int* __restrict__ spn,
                                              int* __restrict__ row,
                                              int* __restrict__ cur,
                                              float* __restrict__ dinv) {
    __shared__ int sm[256];
    int chunk = blockIdx.x, t = threadIdx.x;
    int base = chunk * 1024 + t * 4;
    int v[4];
    #pragma unroll
    for (int k = 0; k < 4; ++k) { int i = base + k; v[k] = (i < N_NODES) ? cnt[i] : 0; }
    int tsum = v[0] + v[1] + v[2] + v[3];
    sm[t] = tsum; __syncthreads();
    for (int off = 1; off < 256; off <<= 1) {       // Hillis-Steele inclusive
        int x = (t >= off) ? sm[t - off] : 0;
        __syncthreads();
        sm[t] += x;
        __syncthreads();
    }
    int excl = spn[chunk] + sm[t] - tsum;
    int run = 0;
    #pragma unroll
    for (int k = 0; k < 4; ++k) {
        int i = base + k;
        if (i < N_NODES) {
            int o = excl + run;
            row[i] = o; cur[i] = o;
            dinv[i] = rsqrtf((float)v[k] + 1.0f);   // +1 = self loop
        }
        run += v[k];
    }
}

// Pass B: bucket = bid&15 (constant XCD class per bucket): cur/ssrc slices
// stay hot in one XCD's L2, lines fill fully before eviction.
__global__ __launch_bounds__(256) void k_place(
    const unsigned long long* __restrict__ pairs,
    const int* __restrict__ bcur,
    int* __restrict__ cur, int* __restrict__ ssrc)
{
    const int bkt = blockIdx.x & 15;
    const int sub = blockIdx.x >> 4;
    const int tid = threadIdx.x;
    for (int rep = 0; rep < 8; ++rep) {
        int n = bcur[bkt * 8 + rep];
        if (n > BCAP) n = BCAP;
        const unsigned long long* p = &pairs[(size_t)(bkt * 8 + rep) * BCAP];
        for (int i = sub * 256 + tid; i < n; i += BPB * 256) {
            unsigned long long pr = p[i];
            int s = (int)(unsigned int)(pr & 0xffffffffull);
            int d = (int)(pr >> 32);
            int slot = atomicAdd(&cur[d], 1);
            ssrc[slot] = s;
        }
    }
}

// Y[r,:] = dinv[r] * ( T(X[r,:]) @ W ); T = identity or relu(dinv*x + b1).
// Transposed A-tile in LDS (broadcast b128 reads), float4 B-reads (2-way = free),
// thread tile 4 rows x JN cols (cols tx*4 and 64+tx*4 for BN=128).
template<int BN, bool PRE>
__global__ __launch_bounds__(256) void k_gemm(
    const float* __restrict__ X, const float* __restrict__ W,
    const float* __restrict__ bpre, const float* __restrict__ dinv,
    float* __restrict__ Y)
{
    constexpr int JN = BN / 16;
    __shared__ __align__(16) float xs[64][68];   // TRANSPOSED: xs[k][row]
    __shared__ __align__(16) float ws[64][BN];
    const int tid = threadIdx.x;
    const int tx = tid & 15, ty = tid >> 4;
    const int row0 = blockIdx.x * 64;

    float acc[4][JN];
    #pragma unroll
    for (int i = 0; i < 4; ++i)
        #pragma unroll
        for (int j = 0; j < JN; ++j) acc[i][j] = 0.f;

    for (int k0 = 0; k0 < 128; k0 += 64) {
        #pragma unroll
        for (int p = 0; p < 4; ++p) {
            int r = p * 16 + ty;
            int c = tx * 4;
            int gr = row0 + r;
            float4 v = make_float4(0.f, 0.f, 0.f, 0.f);
            if (gr < N_NODES) v = *(const float4*)&X[(size_t)gr * 128 + k0 + c];
            if constexpr (PRE) {
                float dv = (gr < N_NODES) ? dinv[gr] : 0.f;
                const float4 bb = *(const float4*)&bpre[k0 + c];
                v.x = fmaxf(fmaf(dv, v.x, bb.x), 0.f);
                v.y = fmaxf(fmaf(dv, v.y, bb.y), 0.f);
                v.z = fmaxf(fmaf(dv, v.z, bb.z), 0.f);
                v.w = fmaxf(fmaf(dv, v.w, bb.w), 0.f);
            }
            xs[c + 0][r] = v.x; xs[c + 1][r] = v.y;
            xs[c + 2][r] = v.z; xs[c + 3][r] = v.w;
        }
        #pragma unroll
        for (int i4 = tid; i4 < 64 * BN / 4; i4 += 256) {
            int r = i4 / (BN / 4);
            int c = (i4 % (BN / 4)) * 4;
            *(float4*)&ws[r][c] = *(const float4*)&W[(k0 + r) * BN + c];
        }
        __syncthreads();
        #pragma unroll 8
        for (int kk = 0; kk < 64; ++kk) {
            float4 a4 = *(const float4*)&xs[kk][ty * 4];
            float av[4] = {a4.x, a4.y, a4.z, a4.w};
            float4 b0 = *(const float4*)&ws[kk][tx * 4];
            float bv[4] = {b0.x, b0.y, b0.z, b0.w};
            #pragma unroll
            for (int i = 0; i < 4; ++i)
                #pragma unroll
                for (int j = 0; j < 4; ++j)
                    acc[i][j] = fmaf(av[i], bv[j], acc[i][j]);
            if constexpr (BN == 128) {
                float4 b1 = *(const float4*)&ws[kk][64 + tx * 4];
                float bw[4] = {b1.x, b1.y, b1.z, b1.w};
                #pragma unroll
                for (int i = 0; i < 4; ++i)
                    #pragma unroll
                    for (int j = 0; j < 4; ++j)
                        acc[i][4 + j] = fmaf(av[i], bw[j], acc[i][4 + j]);
            }
        }
        __syncthreads();
    }
    #pragma unroll
    for (int i = 0; i < 4; ++i) {
        int r = row0 + ty * 4 + i;
        if (r < N_NODES) {
            float dv = dinv[r];
            float4 o0;
            o0.x = acc[i][0] * dv; o0.y = acc[i][1] * dv;
            o0.z = acc[i][2] * dv; o0.w = acc[i][3] * dv;
            *(float4*)&Y[(size_t)r * BN + tx * 4] = o0;
            if constexpr (BN == 128) {
                float4 o1;
                o1.x = acc[i][4] * dv; o1.y = acc[i][5] * dv;
                o1.z = acc[i][6] * dv; o1.w = acc[i][7] * dv;
                *(float4*)&Y[(size_t)r * BN + 64 + tx * 4] = o1;
            }
        }
    }
}

// one wave per dst node: agg[d,:] = hs[d,:] + sum over edges hs[src,:]
template<int COLS>
__global__ __launch_bounds__(256) void k_gather(
    const int* __restrict__ ssrc, const int* __restrict__ row,
    const int* __restrict__ cnt, const float* __restrict__ hs,
    float* __restrict__ agg)
{
    const int node = (blockIdx.x * 256 + threadIdx.x) >> 6;   // uniform per wave
    const int lane = threadIdx.x & 63;
    if (node >= N_NODES) return;
    const int beg = row[node];
    const int num = cnt[node];

    if constexpr (COLS == 128) {
        const float2* hp = (const float2*)hs;
        float2 acc = hp[(size_t)node * 64 + lane];            // self loop
        for (int e0 = 0; e0 < num; e0 += 64) {
            int nb = num - e0; if (nb > 64) nb = 64;
            int sl = (e0 + lane < num) ? ssrc[beg + e0 + lane] : 0;
            int j = 0;
            for (; j + 4 <= nb; j += 4) {
                int s0 = __shfl(sl, j),     s1 = __shfl(sl, j + 1);
                int s2 = __shfl(sl, j + 2), s3 = __shfl(sl, j + 3);
                float2 a = hp[(size_t)s0 * 64 + lane];
                float2 b = hp[(size_t)s1 * 64 + lane];
                float2 c = hp[(size_t)s2 * 64 + lane];
                float2 d = hp[(size_t)s3 * 64 + lane];
                acc.x += a.x; acc.y += a.y; acc.x += b.x; acc.y += b.y;
                acc.x += c.x; acc.y += c.y; acc.x += d.x; acc.y += d.y;
            }
            for (; j < nb; ++j) {
                int s = __shfl(sl, j);
                float2 a = hp[(size_t)s * 64 + lane];
                acc.x += a.x; acc.y += a.y;
            }
        }
        ((float2*)agg)[(size_t)node * 64 + lane] = acc;
    } else {
        float acc = hs[(size_t)node * 64 + lane];             // self loop
        for (int e0 = 0; e0 < num; e0 += 64) {
            int nb = num - e0; if (nb > 64) nb = 64;
            int sl = (e0 + lane < num) ? ssrc[beg + e0 + lane] : 0;
            int j = 0;
            for (; j + 4 <= nb; j += 4) {
                int s0 = __shfl(sl, j),     s1 = __shfl(sl, j + 1);
                int s2 = __shfl(sl, j + 2), s3 = __shfl(sl, j + 3);
                float a = hs[(size_t)s0 * 64 + lane];
                float b = hs[(size_t)s1 * 64 + lane];
                float c = hs[(size_t)s2 * 64 + lane];
                float d = hs[(size_t)s3 * 64 + lane];
                acc += a; acc += b; acc += c; acc += d;
            }
            for (; j < nb; ++j) {
                int s = __shfl(sl, j);
                acc += hs[(size_t)s * 64 + lane];
            }
        }
        agg[(size_t)node * 64 + lane] = acc;
    }
}

// out[node,:] = log_softmax( relu(dinv*agg2 + b2) @ Wfc + bfc )
__global__ __launch_bounds__(256) void k_final(
    const float* __restrict__ agg2, const float* __restrict__ dinv,
    const float* __restrict__ b2, const float* __restrict__ Wfc,
    const float* __restrict__ bfc, float* __restrict__ out)
{
    __shared__ float wfc[64][16];
    __shared__ float sb2[64];
    __shared__ float sbfc[16];
    int tid = threadIdx.x;
    for (int i = tid; i < 64 * 16; i += 256) wfc[i >> 4][i & 15] = Wfc[i];
    if (tid < 64) sb2[tid] = b2[tid];
    if (tid < 16) sbfc[tid] = bfc[tid];
    __syncthreads();
    int node = blockIdx.x * 256 + tid;
    if (node >= N_NODES) return;
    float dv = dinv[node];
    float l[16];
    #pragma unroll
    for (int j = 0; j < 16; ++j) l[j] = sbfc[j];
    const float4* rowp = (const float4*)&agg2[(size_t)node * 64];
    #pragma unroll
    for (int k4 = 0; k4 < 16; ++k4) {
        float4 v = rowp[k4];
        float h[4];
        h[0] = fmaxf(fmaf(dv, v.x, sb2[k4 * 4 + 0]), 0.f);
        h[1] = fmaxf(fmaf(dv, v.y, sb2[k4 * 4 + 1]), 0.f);
        h[2] = fmaxf(fmaf(dv, v.z, sb2[k4 * 4 + 2]), 0.f);
        h[3] = fmaxf(fmaf(dv, v.w, sb2[k4 * 4 + 3]), 0.f);
        #pragma unroll
        for (int u = 0; u < 4; ++u)
            #pragma unroll
            for (int j = 0; j < 16; ++j)
                l[j] = fmaf(h[u], wfc[k4 * 4 + u][j], l[j]);
    }
    float m = l[0];
    #pragma unroll
    for (int j = 1; j < 16; ++j) m = fmaxf(m, l[j]);
    float sum = 0.f;
    #pragma unroll
    for (int j = 0; j < 16; ++j) sum += expf(l[j] - m);
    float ls = logf(sum);
    float* o = &out[(size_t)node * 16];
    #pragma unroll
    for (int j = 0; j < 16; ++j) o[j] = l[j] - m - ls;
}

extern "C" void kernel_launch(void* const* d_in, const int* in_sizes, int n_in,
                              void* d_out, int out_size, void* d_ws, size_t ws_size,
                              hipStream_t stream) {
    const float* x   = (const float*)d_in[0];
    const int* ei    = (const int*)d_in[1];   // int32 [2, E]
    const float* W1  = (const float*)d_in[2];
    const float* b1  = (const float*)d_in[3];
    const float* W2  = (const float*)d_in[4];
    const float* b2  = (const float*)d_in[5];
    const float* Wfc = (const float*)d_in[6];
    const float* bfc = (const float*)d_in[7];
    float* out = (float*)d_out;

    char* ws = (char*)d_ws;
    int*   cnt   = (int*)(ws + OFF_CNT);
    int*   bcur  = (int*)(ws + OFF_BCUR);
    float* dinv  = (float*)(ws + OFF_DINV);
    int*   row   = (int*)(ws + OFF_ROW);
    int*   cur   = (int*)(ws + OFF_CUR);
    int*   spn   = (int*)(ws + OFF_SPN);
    int*   ssrc  = (int*)(ws + OFF_SSRC);
    float* bufA  = (float*)(ws + OFF_A);
    float* bufB  = (float*)(ws + OFF_B);
    unsigned long long* pairs = (unsigned long long*)(ws + OFF_B);  // alias, pre-gather
    const int* src = ei;
    const int* dst = ei + N_EDGES;

    // ---- CSR build (by dst) ----
    hipMemsetAsync(cnt, 0, 400512, stream);   // cnt + bcur
    k_bucket<<<(N_EDGES + 255) / 256, 256, 0, stream>>>(src, dst, cnt, bcur, pairs);
    k_sum<<<NCHUNK, 256, 0, stream>>>(cnt, spn);
    k_spine<<<1, 64, 0, stream>>>(spn);
    k_scan<<<NCHUNK, 256, 0, stream>>>(cnt, spn, row, cur, dinv);
    k_place<<<NBKT * BPB, 256, 0, stream>>>(pairs, bcur, cur, ssrc);

    // ---- layer 1: hs1 = (x @ W1) * dinv -> bufA; agg1 -> bufB ----
    k_gemm<128, false><<<(N_NODES + 63) / 64, 256, 0, stream>>>(x, W1, nullptr, dinv, bufA);
    k_gather<128><<<(N_NODES * 64) / 256, 256, 0, stream>>>(ssrc, row, cnt, bufA, bufB);

    // ---- layer 2: hs2 = (relu(dinv*agg1 + b1) @ W2) * dinv -> bufA; agg2 -> bufB ----
    k_gemm<64, true><<<(N_NODES + 63) / 64, 256, 0, stream>>>(bufB, W2, b1, dinv, bufA);
    k_gather<64><<<(N_NODES * 64) / 256, 256, 0, stream>>>(ssrc, row, cnt, bufA, bufB);

    // ---- final: relu(dinv*agg2 + b2) @ Wfc + bfc -> log_softmax ----
    k_final<<<(N_NODES + 255) / 256, 256, 0, stream>>>(bufB, dinv, b2, Wfc, bfc, out);
}